// Round 14
// baseline (514.986 us; speedup 1.0000x reference)
//
#include <hip/hip_runtime.h>

typedef unsigned long long u64;

// ---------------------------------------------------------------------------
// threebody indices (MatterSim). All outputs int32.
//
// FAST path ws layout (int32):
//   [0, A)            cursor (zeroed; counts after bucket pass)
//   [A, A+2NC)        lb     (u64 lookback flags: state<<32 | value)
//   [A+2NC, A+3NC)    tdone  (per-tile data-ready flags)
//   [M, M+2A)         meta2  (int2 per atom: {c, tstart}),  M = align2(A+3NC)
//   [M+2A, M+3A+1)    tstarts (exclusive scan of c*(c-1); [A]=total)
//   [M+3A+1, +64A)    bucket (CMAX ints per atom)
//
// FALLBACK (round-7) ws layout: counts A | cursor A | starts A | tstarts A+1
//   (pad 4A+4) | meta int4 4A | sorted_bond n_bond | partials 2*NB
// ---------------------------------------------------------------------------

#define CMAX 64    // padded bucket capacity per atom (data max ~30)
#define SBLK 256   // scan tile size / fused block size
#define WPB 4      // waves (atoms) per block in kf_scanpairs (256 thr = 4 waves!)
#define FWPB 4     // fallback k_pairs waves/block
#define BLK 256    // fallback scan block size

__global__ void k_init(int* __restrict__ p, int n) {
    int i = blockIdx.x * blockDim.x + threadIdx.x;
    if (i < n) p[i] = 0;
}

// ============================ FAST PATH ====================================

// One pass over bonds: zero out_ij, scatter kept bonds into padded buckets.
__global__ void kf_bucket(const int2* __restrict__ bai, const float* __restrict__ blen,
                          const float* __restrict__ cutp, int* __restrict__ cursor,
                          int* __restrict__ bucket, int* __restrict__ out_ij,
                          int n_bond) {
    int b = blockIdx.x * blockDim.x + threadIdx.x;
    if (b >= n_bond) return;
    out_ij[b] = 0;                       // kept bonds overwritten by kf_scanpairs
    if (blen[b] <= *cutp) {
        int a = bai[b].x;
        int r = atomicAdd(&cursor[a], 1);
        if (r < CMAX) bucket[(a << 6) + r] = b;
    }
}

// Fused scan + pairs. Blocks < NC first compute their 256-atom scan tile
// (decoupled lookback, wave-parallel 64-wide window) and publish a per-tile
// release flag; all blocks then emit pairs for their WPB(=4) atoms after
// acquiring the owning tile's flag. Tile producers are the lowest block ids
// (dispatched first) and pairs-block blk only waits on tiles <= blk/64:
// deadlock-free under ascending dispatch.
__global__ __launch_bounds__(SBLK) void kf_scanpairs(
        const int* __restrict__ cursor, u64* __restrict__ lb,
        int* __restrict__ tdone, int2* __restrict__ meta2,
        int* __restrict__ tstarts, int* __restrict__ out_ti,
        const int* __restrict__ bucket, int2* __restrict__ out_bi,
        int* __restrict__ out_ij, const int* __restrict__ n_atoms,
        int* __restrict__ out_ns, int S, int A, int NC) {
    int blk = blockIdx.x;
    int lane = threadIdx.x & 63, wv = threadIdx.x >> 6;

    if (blk < NC) {
        // ---- scan tile blk ----
        int i = blk * SBLK + threadIdx.x;
        int c = 0;
        if (i < A) {
            c = cursor[i];
            if (c > CMAX) c = CMAX;      // memory-safety clamp (never hit here)
        }
        int t = c * (c - 1);

        int it = t;                      // inclusive wave scan
        for (int off = 1; off < 64; off <<= 1) {
            int nt = __shfl_up(it, off, 64);
            if (lane >= off) it += nt;
        }
        __shared__ int wt[SBLK / 64];
        __shared__ int s_ex;
        if (lane == 63) wt[wv] = it;
        __syncthreads();
        int bt = 0;
        for (int w = 0; w < wv; ++w) bt += wt[w];
        int tile_ex = bt + it - t;

        int agg = 0;
        for (int w = 0; w < SBLK / 64; ++w) agg += wt[w];

        if (blk == 0) {
            if (threadIdx.x == 0) {
                __hip_atomic_store(&lb[0], (2ull << 32) | (u64)(unsigned)agg,
                                   __ATOMIC_RELEASE, __HIP_MEMORY_SCOPE_AGENT);
                s_ex = 0;
            }
        } else if (wv == 0) {
            if (lane == 0)
                __hip_atomic_store(&lb[blk], (1ull << 32) | (u64)(unsigned)agg,
                                   __ATOMIC_RELEASE, __HIP_MEMORY_SCOPE_AGENT);
            int ex = 0;
            int base = blk - 1;
            for (;;) {
                int j = base - lane;     // lane 0 = nearest predecessor
                unsigned st;
                int val;
                if (j >= 0) {
                    u64 v = __hip_atomic_load(&lb[j], __ATOMIC_ACQUIRE,
                                              __HIP_MEMORY_SCOPE_AGENT);
                    st = (unsigned)(v >> 32);
                    val = (int)(unsigned)(v & 0xffffffffull);
                } else {                 // below block 0: virtual prefix 0
                    st = 2u;
                    val = 0;
                }
                u64 b2 = __ballot(st == 2u);
                u64 b0 = __ballot(st == 0u);
                int L2 = b2 ? __builtin_ctzll(b2) : 64;
                u64 need = (L2 >= 63) ? ~0ull : ((1ull << (L2 + 1)) - 1ull);
                if ((b0 & need) == 0) {  // all needed entries published
                    int vsum = (L2 >= 64 || lane <= L2) ? val : 0;
                    for (int off = 32; off; off >>= 1)
                        vsum += __shfl_xor(vsum, off, 64);
                    ex += vsum;
                    if (L2 < 64) break;  // consumed an inclusive prefix
                    base -= 64;          // window all aggregates: widen
                }
            }
            if (lane == 0) {
                __hip_atomic_store(&lb[blk],
                                   (2ull << 32) | (u64)(unsigned)(ex + agg),
                                   __ATOMIC_RELEASE, __HIP_MEMORY_SCOPE_AGENT);
                s_ex = ex;
            }
        }
        __syncthreads();

        int tx = s_ex + tile_ex;
        if (i < A) {
            tstarts[i] = tx;
            meta2[i] = make_int2(c, tx);
            out_ti[i] = t;
            if (i == A - 1) tstarts[A] = tx + t;
        }
        __syncthreads();
        __threadfence();
        if (threadIdx.x == 0)
            __hip_atomic_store(&tdone[blk], 1, __ATOMIC_RELEASE,
                               __HIP_MEMORY_SCOPE_AGENT);
    }

    // ---- out_ns (block 0; waits on boundary tiles) ----
    if (blk == 0 && threadIdx.x < S) {
        int s = threadIdx.x;
        int blo = 0;
        for (int k = 0; k < s; ++k) blo += n_atoms[k];
        int bhi = blo + n_atoms[s];
        int t1 = blo >> 8; if (t1 >= NC) t1 = NC - 1;
        int t2 = (bhi >= A) ? (NC - 1) : (bhi >> 8);
        while (__hip_atomic_load(&tdone[t1], __ATOMIC_ACQUIRE,
                                 __HIP_MEMORY_SCOPE_AGENT) == 0) {}
        while (__hip_atomic_load(&tdone[t2], __ATOMIC_ACQUIRE,
                                 __HIP_MEMORY_SCOPE_AGENT) == 0) {}
        out_ns[s] = tstarts[bhi] - tstarts[blo];
    }

    // ---- pairs: one wave per atom (4 waves/block) ----
    int a = blk * WPB + wv;
    if (a >= A) return;
    int tile = a >> 8;                    // SBLK = 256
    while (__hip_atomic_load(&tdone[tile], __ATOMIC_ACQUIRE,
                             __HIP_MEMORY_SCOPE_AGENT) == 0) {}

    int2 m = meta2[a];
    int c = m.x;
    if (c < 1) return;

    int v = (lane < c) ? bucket[(a << 6) + lane] : 0x7fffffff;
    if (lane < c) out_ij[v] = c - 1;      // covers c==1 (writes 0) and c>=2
    if (c < 2) return;

    int rank = 0;
    for (int j = 0; j < c; ++j) {
        int vj = __shfl(v, j, 64);
        rank += (vj < v) ? 1 : 0;
    }
    int sv = __builtin_amdgcn_ds_permute(rank << 2, v);

    int P = (c * (c - 1)) >> 1;           // (i<j) combos
    int2* outp = out_bi + m.y;            // atom block: 2P int2 (P fwd + P flip)
    int niter = (P + 63) >> 6;
    for (int it = 0; it < niter; ++it) {
        int p = (it << 6) + lane;
        bool act = p < P;
        int pp = act ? p : 0;
        int i = 0, rem = pp;
        while (rem >= c - 1 - i) { rem -= c - 1 - i; ++i; }
        int j = i + 1 + rem;
        int bi = __shfl(sv, i, 64);
        int bj = __shfl(sv, j, 64);
        if (act) {
            outp[p]     = make_int2(bi, bj);
            outp[P + p] = make_int2(bj, bi);
        }
    }
}

// =========================== FALLBACK (round 7) ============================
__global__ void k_count(const int2* __restrict__ bai, const float* __restrict__ blen,
                        const float* __restrict__ cutp, int* __restrict__ counts,
                        int n_bond) {
    int b = blockIdx.x * blockDim.x + threadIdx.x;
    if (b >= n_bond) return;
    if (blen[b] <= *cutp) atomicAdd(&counts[bai[b].x], 1);
}

__global__ __launch_bounds__(BLK) void k_part(const int* __restrict__ counts,
                                              int2* __restrict__ partials, int A) {
    int i = blockIdx.x * BLK + threadIdx.x;
    int c = (i < A) ? counts[i] : 0;
    int t = c * (c - 1);
    int lane = threadIdx.x & 63, wv = threadIdx.x >> 6;
    for (int off = 32; off; off >>= 1) {
        c += __shfl_down(c, off, 64);
        t += __shfl_down(t, off, 64);
    }
    __shared__ int sc[BLK / 64], st[BLK / 64];
    if (lane == 0) { sc[wv] = c; st[wv] = t; }
    __syncthreads();
    if (threadIdx.x == 0) {
        int tc = 0, tt = 0;
        for (int w = 0; w < BLK / 64; ++w) { tc += sc[w]; tt += st[w]; }
        partials[blockIdx.x] = make_int2(tc, tt);
    }
}

__global__ __launch_bounds__(1024) void k_mid(int2* __restrict__ partials, int NB,
                                              int* __restrict__ totp) {
    const int T = 1024;
    __shared__ int sc[T], st[T];
    int tid = threadIdx.x;
    int chunk = (NB + T - 1) / T;
    int lo = tid * chunk, hi = lo + chunk;
    if (hi > NB) hi = NB;
    int pc = 0, pt = 0;
    for (int i = lo; i < hi; ++i) { pc += partials[i].x; pt += partials[i].y; }
    sc[tid] = pc; st[tid] = pt;
    __syncthreads();
    for (int off = 1; off < T; off <<= 1) {
        int vc = 0, vt = 0;
        if (tid >= off) { vc = sc[tid - off]; vt = st[tid - off]; }
        __syncthreads();
        sc[tid] += vc; st[tid] += vt;
        __syncthreads();
    }
    int rc = sc[tid] - pc, rt = st[tid] - pt;
    for (int i = lo; i < hi; ++i) {
        int2 v = partials[i];
        partials[i] = make_int2(rc, rt);
        rc += v.x; rt += v.y;
    }
    if (tid == T - 1) *totp = rt;
}

__global__ __launch_bounds__(BLK) void k_final(const int* __restrict__ counts,
                                               const int2* __restrict__ partials,
                                               int* __restrict__ starts,
                                               int* __restrict__ tstarts,
                                               int4* __restrict__ meta,
                                               int* __restrict__ out_ti,
                                               int* __restrict__ cursor, int A) {
    int i = blockIdx.x * BLK + threadIdx.x;
    int c = (i < A) ? counts[i] : 0;
    int t = c * (c - 1);
    int lane = threadIdx.x & 63, wv = threadIdx.x >> 6;
    int ic = c, it = t;
    for (int off = 1; off < 64; off <<= 1) {
        int nc = __shfl_up(ic, off, 64), nt = __shfl_up(it, off, 64);
        if (lane >= off) { ic += nc; it += nt; }
    }
    __shared__ int wc[BLK / 64], wt[BLK / 64];
    if (lane == 63) { wc[wv] = ic; wt[wv] = it; }
    __syncthreads();
    int bc = 0, bt = 0;
    for (int w = 0; w < wv; ++w) { bc += wc[w]; bt += wt[w]; }
    int2 bo = partials[blockIdx.x];
    int sx = bo.x + bc + ic - c;
    int tx = bo.y + bt + it - t;
    if (i < A) {
        starts[i] = sx;
        tstarts[i] = tx;
        meta[i] = make_int4(c, sx, tx, 0);
        out_ti[i] = t;
        cursor[i] = sx;
        if (i == A - 1) tstarts[A] = tx + t;
    }
}

__global__ void k_scatter(const int2* __restrict__ bai, const float* __restrict__ blen,
                          const float* __restrict__ cutp, const int4* __restrict__ meta,
                          int* __restrict__ cursor, int* __restrict__ sorted_bond,
                          int* __restrict__ out_ij, int n_bond) {
    int b = blockIdx.x * blockDim.x + threadIdx.x;
    if (b >= n_bond) return;
    if (blen[b] <= *cutp) {
        int c = bai[b].x;
        int cnt = meta[c].x;
        out_ij[b] = cnt > 1 ? cnt - 1 : 0;
        int r = atomicAdd(&cursor[c], 1);
        sorted_bond[r] = b;
    } else {
        out_ij[b] = 0;
    }
}

__global__ __launch_bounds__(FWPB * 64) void k_pairs(
        const int4* __restrict__ meta, int* __restrict__ sorted_bond,
        int2* __restrict__ out_bi, const int* __restrict__ tstarts,
        const int* __restrict__ n_atoms, int* __restrict__ out_ns,
        int S, int A) {
    if (blockIdx.x == 0 && threadIdx.x < S) {
        int s = threadIdx.x;
        int blo = 0;
        for (int k = 0; k < s; ++k) blo += n_atoms[k];
        int bhi = blo + n_atoms[s];
        out_ns[s] = tstarts[bhi] - tstarts[blo];
    }

    int wv = threadIdx.x >> 6;
    int lane = threadIdx.x & 63;
    int a = blockIdx.x * FWPB + wv;
    if (a >= A) return;

    int4 m = meta[a];
    int c = m.x;
    if (c < 2) return;
    int st0 = m.y;
    int P = (c * (c - 1)) >> 1;
    int2* outp = out_bi + m.z;

    if (c <= 64) {
        int v = (lane < c) ? sorted_bond[st0 + lane] : 0x7fffffff;
        int rank = 0;
        for (int j = 0; j < c; ++j) {
            int vj = __shfl(v, j, 64);
            rank += (vj < v) ? 1 : 0;
        }
        int sv = __builtin_amdgcn_ds_permute(rank << 2, v);

        int niter = (P + 63) >> 6;
        for (int it = 0; it < niter; ++it) {
            int p = (it << 6) + lane;
            bool act = p < P;
            int pp = act ? p : 0;
            int i = 0, rem = pp;
            while (rem >= c - 1 - i) { rem -= c - 1 - i; ++i; }
            int j = i + 1 + rem;
            int bi = __shfl(sv, i, 64);
            int bj = __shfl(sv, j, 64);
            if (act) {
                outp[p]     = make_int2(bi, bj);
                outp[P + p] = make_int2(bj, bi);
            }
        }
    } else if (lane == 0) {
        for (int i = 1; i < c; ++i) {
            int v = sorted_bond[st0 + i];
            int j = i - 1;
            while (j >= 0 && sorted_bond[st0 + j] > v) {
                sorted_bond[st0 + j + 1] = sorted_bond[st0 + j];
                --j;
            }
            sorted_bond[st0 + j + 1] = v;
        }
        int p = 0;
        for (int i = 0; i < c; ++i) {
            int bi = sorted_bond[st0 + i];
            for (int j = i + 1; j < c; ++j) {
                int bj = sorted_bond[st0 + j];
                outp[p]     = make_int2(bi, bj);
                outp[P + p] = make_int2(bj, bi);
                ++p;
            }
        }
    }
}

extern "C" void kernel_launch(void* const* d_in, const int* in_sizes, int n_in,
                              void* d_out, int out_size, void* d_ws, size_t ws_size,
                              hipStream_t stream) {
    const int2* bai     = (const int2*)d_in[0];   // [n_bond,2] int32
    const float* blen   = (const float*)d_in[1];  // [n_bond] f32
    const int* n_atoms  = (const int*)d_in[2];    // [S] int32
    // d_in[3] = atomic_number (unused)
    const float* cutp   = (const float*)d_in[4];  // scalar f32

    int n_bond = in_sizes[1];
    int S      = in_sizes[2];
    int A      = in_sizes[3];

    int n_tr2 = out_size - n_bond - A - S;  // 2 * n_triple

    int* out     = (int*)d_out;
    int2* out_bi = (int2*)out;          // [n_triple] pairs
    int* out_ij  = out + n_tr2;         // [n_bond]
    int* out_ti  = out_ij + n_bond;     // [A]
    int* out_ns  = out_ti + A;          // [S]

    int* ws = (int*)d_ws;
    int NC = (A + SBLK - 1) / SBLK;

    // fast-path layout
    int meta2_off = (A + 3 * NC + 1) & ~1;          // int2 needs 8B align
    long long need_fast = (long long)meta2_off + 3LL * A + 1 + 64LL * A;
    bool fast = ((long long)(ws_size / 4) >= need_fast) && (NC <= 1024) &&
                (S <= 64) && ((A & 1) == 0);

    if (fast) {
        int* cursor   = ws;                          // A
        u64* lb       = (u64*)(ws + A);              // NC u64
        int* tdone    = ws + A + 2 * NC;             // NC
        int2* meta2   = (int2*)(ws + meta2_off);     // A int2
        int* tstarts  = ws + meta2_off + 2 * A;      // A+1
        int* bucket   = ws + meta2_off + 3 * A + 1;  // 64*A

        int NP = (A + WPB - 1) / WPB;                // 4 atoms (waves) per block

        k_init<<<(A + 3 * NC + 255) / 256, 256, 0, stream>>>(cursor, A + 3 * NC);
        kf_bucket<<<(n_bond + 255) / 256, 256, 0, stream>>>(bai, blen, cutp, cursor,
                                                            bucket, out_ij, n_bond);
        kf_scanpairs<<<NP, SBLK, 0, stream>>>(cursor, lb, tdone, meta2, tstarts,
                                              out_ti, bucket, out_bi, out_ij,
                                              n_atoms, out_ns, S, A, NC);
    } else {
        int* counts      = ws;
        int* cursor      = ws + A;
        int* starts      = ws + 2 * A;
        int* tstarts     = ws + 3 * A;                  // A+1, padded to 4A+4
        int4* meta       = (int4*)(ws + 4 * A + 4);
        int* sorted_bond = ws + 8 * A + 4;
        int2* partials   = (int2*)(ws + 8 * A + 4 + n_bond);
        int NB = (A + BLK - 1) / BLK;

        k_init<<<(A + 255) / 256, 256, 0, stream>>>(counts, A);
        k_count<<<(n_bond + 255) / 256, 256, 0, stream>>>(bai, blen, cutp, counts, n_bond);
        k_part<<<NB, BLK, 0, stream>>>(counts, partials, A);
        k_mid<<<1, 1024, 0, stream>>>(partials, NB, &tstarts[A]);
        k_final<<<NB, BLK, 0, stream>>>(counts, partials, starts, tstarts, meta, out_ti,
                                        cursor, A);
        k_scatter<<<(n_bond + 255) / 256, 256, 0, stream>>>(bai, blen, cutp, meta,
                                                            cursor, sorted_bond, out_ij,
                                                            n_bond);
        k_pairs<<<(A + FWPB - 1) / FWPB, FWPB * 64, 0, stream>>>(meta, sorted_bond,
                                                                 out_bi, tstarts,
                                                                 n_atoms, out_ns, S, A);
    }
}

// Round 15
// 157.437 us; speedup vs baseline: 3.2711x; 3.2711x over previous
//
#include <hip/hip_runtime.h>

typedef unsigned long long u64;

// ---------------------------------------------------------------------------
// threebody indices (MatterSim). All outputs int32.
//
// FAST path ws layout (int32):
//   [0, A)            cursor (zeroed; counts after bucket pass)
//   [A, A+2NC)        lb     (u64 lookback flags: state<<32 | value)
//   [A+2NC, A+3NC)    tdone  (per-tile data-ready flags)
//   [M, M+2A)         meta2  (int2 per atom: {c, tstart}),  M = align2(A+3NC)
//   [M+2A, M+3A+1)    tstarts (exclusive scan of c*(c-1); [A]=total)
//   [M+3A+1, +64A)    bucket (CMAX ints per atom)
//
// FALLBACK (round-7) ws layout: counts A | cursor A | starts A | tstarts A+1
//   (pad 4A+4) | meta int4 4A | sorted_bond n_bond | partials 2*NB
// ---------------------------------------------------------------------------

#define CMAX 64    // padded bucket capacity per atom (data max ~30)
#define SBLK 256   // scan tile size / fused block size
#define WPB 4      // waves (atoms) per block in kf_scanpairs (256 thr = 4 waves)
#define FWPB 4     // fallback k_pairs waves/block
#define BLK 256    // fallback scan block size

__global__ void k_init(int* __restrict__ p, int n) {
    int i = blockIdx.x * blockDim.x + threadIdx.x;
    if (i < n) p[i] = 0;
}

// ============================ FAST PATH ====================================

// One pass over bonds: zero out_ij, scatter kept bonds into padded buckets.
__global__ void kf_bucket(const int2* __restrict__ bai, const float* __restrict__ blen,
                          const float* __restrict__ cutp, int* __restrict__ cursor,
                          int* __restrict__ bucket, int* __restrict__ out_ij,
                          int n_bond) {
    int b = blockIdx.x * blockDim.x + threadIdx.x;
    if (b >= n_bond) return;
    out_ij[b] = 0;                       // kept bonds overwritten by kf_scanpairs
    if (blen[b] <= *cutp) {
        int a = bai[b].x;
        int r = atomicAdd(&cursor[a], 1);
        if (r < CMAX) bucket[(a << 6) + r] = b;
    }
}

__device__ __forceinline__ void wait_tile(const int* tdone, int t) {
    // fast check, then backoff-polled wait (~1000 cycles between polls)
    if (__hip_atomic_load(&tdone[t], __ATOMIC_ACQUIRE,
                          __HIP_MEMORY_SCOPE_AGENT) != 0) return;
    for (;;) {
        __builtin_amdgcn_s_sleep(16);
        if (__hip_atomic_load(&tdone[t], __ATOMIC_ACQUIRE,
                              __HIP_MEMORY_SCOPE_AGENT) != 0) return;
    }
}

// Fused scan + pairs. Blocks < NC first compute their 256-atom scan tile
// (decoupled lookback, wave-parallel 64-wide window) and publish a per-tile
// release flag. All blocks then wait (ONE poller per block, s_sleep backoff)
// for the <=2 tiles covering their WPB(=4) atoms and emit pairs. Tile
// producers are the lowest block ids (dispatched first): deadlock-free.
__global__ __launch_bounds__(SBLK) void kf_scanpairs(
        const int* __restrict__ cursor, u64* __restrict__ lb,
        int* __restrict__ tdone, int2* __restrict__ meta2,
        int* __restrict__ tstarts, int* __restrict__ out_ti,
        const int* __restrict__ bucket, int2* __restrict__ out_bi,
        int* __restrict__ out_ij, const int* __restrict__ n_atoms,
        int* __restrict__ out_ns, int S, int A, int NC) {
    int blk = blockIdx.x;
    int lane = threadIdx.x & 63, wv = threadIdx.x >> 6;

    if (blk < NC) {
        // ---- scan tile blk ----
        int i = blk * SBLK + threadIdx.x;
        int c = 0;
        if (i < A) {
            c = cursor[i];
            if (c > CMAX) c = CMAX;      // memory-safety clamp (never hit here)
        }
        int t = c * (c - 1);

        int it = t;                      // inclusive wave scan
        for (int off = 1; off < 64; off <<= 1) {
            int nt = __shfl_up(it, off, 64);
            if (lane >= off) it += nt;
        }
        __shared__ int wt[SBLK / 64];
        __shared__ int s_ex;
        if (lane == 63) wt[wv] = it;
        __syncthreads();
        int bt = 0;
        for (int w = 0; w < wv; ++w) bt += wt[w];
        int tile_ex = bt + it - t;

        int agg = 0;
        for (int w = 0; w < SBLK / 64; ++w) agg += wt[w];

        if (blk == 0) {
            if (threadIdx.x == 0) {
                __hip_atomic_store(&lb[0], (2ull << 32) | (u64)(unsigned)agg,
                                   __ATOMIC_RELEASE, __HIP_MEMORY_SCOPE_AGENT);
                s_ex = 0;
            }
        } else if (wv == 0) {
            if (lane == 0)
                __hip_atomic_store(&lb[blk], (1ull << 32) | (u64)(unsigned)agg,
                                   __ATOMIC_RELEASE, __HIP_MEMORY_SCOPE_AGENT);
            int ex = 0;
            int base = blk - 1;
            for (;;) {
                int j = base - lane;     // lane 0 = nearest predecessor
                unsigned st;
                int val;
                if (j >= 0) {
                    u64 v = __hip_atomic_load(&lb[j], __ATOMIC_ACQUIRE,
                                              __HIP_MEMORY_SCOPE_AGENT);
                    st = (unsigned)(v >> 32);
                    val = (int)(unsigned)(v & 0xffffffffull);
                } else {                 // below block 0: virtual prefix 0
                    st = 2u;
                    val = 0;
                }
                u64 b2 = __ballot(st == 2u);
                u64 b0 = __ballot(st == 0u);
                int L2 = b2 ? __builtin_ctzll(b2) : 64;
                u64 need = (L2 >= 63) ? ~0ull : ((1ull << (L2 + 1)) - 1ull);
                if ((b0 & need) == 0) {  // all needed entries published
                    int vsum = (L2 >= 64 || lane <= L2) ? val : 0;
                    for (int off = 32; off; off >>= 1)
                        vsum += __shfl_xor(vsum, off, 64);
                    ex += vsum;
                    if (L2 < 64) break;  // consumed an inclusive prefix
                    base -= 64;          // window all aggregates: widen
                }
            }
            if (lane == 0) {
                __hip_atomic_store(&lb[blk],
                                   (2ull << 32) | (u64)(unsigned)(ex + agg),
                                   __ATOMIC_RELEASE, __HIP_MEMORY_SCOPE_AGENT);
                s_ex = ex;
            }
        }
        __syncthreads();

        int tx = s_ex + tile_ex;
        if (i < A) {
            tstarts[i] = tx;
            meta2[i] = make_int2(c, tx);
            out_ti[i] = t;
            if (i == A - 1) tstarts[A] = tx + t;
        }
        __syncthreads();
        __threadfence();
        if (threadIdx.x == 0)
            __hip_atomic_store(&tdone[blk], 1, __ATOMIC_RELEASE,
                               __HIP_MEMORY_SCOPE_AGENT);
    }

    // ---- block-level wait for the tiles covering this block's atoms ----
    int a0 = blk * WPB;
    if (a0 >= A) return;
    int aLast = a0 + WPB - 1;
    if (aLast >= A) aLast = A - 1;
    int tlo = a0 >> 8, thi = aLast >> 8;          // SBLK = 256
    if (threadIdx.x == 0) {
        wait_tile(tdone, tlo);
        if (thi != tlo) wait_tile(tdone, thi);
    }
    __syncthreads();

    // ---- out_ns (block 0; boundary tiles, backoff-polled) ----
    if (blk == 0 && threadIdx.x < S) {
        int s = threadIdx.x;
        int blo = 0;
        for (int k = 0; k < s; ++k) blo += n_atoms[k];
        int bhi = blo + n_atoms[s];
        int t1 = blo >> 8; if (t1 >= NC) t1 = NC - 1;
        int t2 = (bhi >= A) ? (NC - 1) : (bhi >> 8);
        wait_tile(tdone, t1);
        wait_tile(tdone, t2);
        out_ns[s] = tstarts[bhi] - tstarts[blo];
    }

    // ---- pairs: one wave per atom (4 waves/block) ----
    int a = a0 + wv;
    if (a >= A) return;

    int2 m = meta2[a];
    int c = m.x;
    if (c < 1) return;

    int v = (lane < c) ? bucket[(a << 6) + lane] : 0x7fffffff;
    if (lane < c) out_ij[v] = c - 1;      // covers c==1 (writes 0) and c>=2
    if (c < 2) return;

    int rank = 0;
    for (int j = 0; j < c; ++j) {
        int vj = __shfl(v, j, 64);
        rank += (vj < v) ? 1 : 0;
    }
    int sv = __builtin_amdgcn_ds_permute(rank << 2, v);

    int P = (c * (c - 1)) >> 1;           // (i<j) combos
    int2* outp = out_bi + m.y;            // atom block: 2P int2 (P fwd + P flip)
    int niter = (P + 63) >> 6;
    for (int it = 0; it < niter; ++it) {
        int p = (it << 6) + lane;
        bool act = p < P;
        int pp = act ? p : 0;
        int i = 0, rem = pp;
        while (rem >= c - 1 - i) { rem -= c - 1 - i; ++i; }
        int j = i + 1 + rem;
        int bi = __shfl(sv, i, 64);
        int bj = __shfl(sv, j, 64);
        if (act) {
            outp[p]     = make_int2(bi, bj);
            outp[P + p] = make_int2(bj, bi);
        }
    }
}

// =========================== FALLBACK (round 7) ============================
__global__ void k_count(const int2* __restrict__ bai, const float* __restrict__ blen,
                        const float* __restrict__ cutp, int* __restrict__ counts,
                        int n_bond) {
    int b = blockIdx.x * blockDim.x + threadIdx.x;
    if (b >= n_bond) return;
    if (blen[b] <= *cutp) atomicAdd(&counts[bai[b].x], 1);
}

__global__ __launch_bounds__(BLK) void k_part(const int* __restrict__ counts,
                                              int2* __restrict__ partials, int A) {
    int i = blockIdx.x * BLK + threadIdx.x;
    int c = (i < A) ? counts[i] : 0;
    int t = c * (c - 1);
    int lane = threadIdx.x & 63, wv = threadIdx.x >> 6;
    for (int off = 32; off; off >>= 1) {
        c += __shfl_down(c, off, 64);
        t += __shfl_down(t, off, 64);
    }
    __shared__ int sc[BLK / 64], st[BLK / 64];
    if (lane == 0) { sc[wv] = c; st[wv] = t; }
    __syncthreads();
    if (threadIdx.x == 0) {
        int tc = 0, tt = 0;
        for (int w = 0; w < BLK / 64; ++w) { tc += sc[w]; tt += st[w]; }
        partials[blockIdx.x] = make_int2(tc, tt);
    }
}

__global__ __launch_bounds__(1024) void k_mid(int2* __restrict__ partials, int NB,
                                              int* __restrict__ totp) {
    const int T = 1024;
    __shared__ int sc[T], st[T];
    int tid = threadIdx.x;
    int chunk = (NB + T - 1) / T;
    int lo = tid * chunk, hi = lo + chunk;
    if (hi > NB) hi = NB;
    int pc = 0, pt = 0;
    for (int i = lo; i < hi; ++i) { pc += partials[i].x; pt += partials[i].y; }
    sc[tid] = pc; st[tid] = pt;
    __syncthreads();
    for (int off = 1; off < T; off <<= 1) {
        int vc = 0, vt = 0;
        if (tid >= off) { vc = sc[tid - off]; vt = st[tid - off]; }
        __syncthreads();
        sc[tid] += vc; st[tid] += vt;
        __syncthreads();
    }
    int rc = sc[tid] - pc, rt = st[tid] - pt;
    for (int i = lo; i < hi; ++i) {
        int2 v = partials[i];
        partials[i] = make_int2(rc, rt);
        rc += v.x; rt += v.y;
    }
    if (tid == T - 1) *totp = rt;
}

__global__ __launch_bounds__(BLK) void k_final(const int* __restrict__ counts,
                                               const int2* __restrict__ partials,
                                               int* __restrict__ starts,
                                               int* __restrict__ tstarts,
                                               int4* __restrict__ meta,
                                               int* __restrict__ out_ti,
                                               int* __restrict__ cursor, int A) {
    int i = blockIdx.x * BLK + threadIdx.x;
    int c = (i < A) ? counts[i] : 0;
    int t = c * (c - 1);
    int lane = threadIdx.x & 63, wv = threadIdx.x >> 6;
    int ic = c, it = t;
    for (int off = 1; off < 64; off <<= 1) {
        int nc = __shfl_up(ic, off, 64), nt = __shfl_up(it, off, 64);
        if (lane >= off) { ic += nc; it += nt; }
    }
    __shared__ int wc[BLK / 64], wt[BLK / 64];
    if (lane == 63) { wc[wv] = ic; wt[wv] = it; }
    __syncthreads();
    int bc = 0, bt = 0;
    for (int w = 0; w < wv; ++w) { bc += wc[w]; bt += wt[w]; }
    int2 bo = partials[blockIdx.x];
    int sx = bo.x + bc + ic - c;
    int tx = bo.y + bt + it - t;
    if (i < A) {
        starts[i] = sx;
        tstarts[i] = tx;
        meta[i] = make_int4(c, sx, tx, 0);
        out_ti[i] = t;
        cursor[i] = sx;
        if (i == A - 1) tstarts[A] = tx + t;
    }
}

__global__ void k_scatter(const int2* __restrict__ bai, const float* __restrict__ blen,
                          const float* __restrict__ cutp, const int4* __restrict__ meta,
                          int* __restrict__ cursor, int* __restrict__ sorted_bond,
                          int* __restrict__ out_ij, int n_bond) {
    int b = blockIdx.x * blockDim.x + threadIdx.x;
    if (b >= n_bond) return;
    if (blen[b] <= *cutp) {
        int c = bai[b].x;
        int cnt = meta[c].x;
        out_ij[b] = cnt > 1 ? cnt - 1 : 0;
        int r = atomicAdd(&cursor[c], 1);
        sorted_bond[r] = b;
    } else {
        out_ij[b] = 0;
    }
}

__global__ __launch_bounds__(FWPB * 64) void k_pairs(
        const int4* __restrict__ meta, int* __restrict__ sorted_bond,
        int2* __restrict__ out_bi, const int* __restrict__ tstarts,
        const int* __restrict__ n_atoms, int* __restrict__ out_ns,
        int S, int A) {
    if (blockIdx.x == 0 && threadIdx.x < S) {
        int s = threadIdx.x;
        int blo = 0;
        for (int k = 0; k < s; ++k) blo += n_atoms[k];
        int bhi = blo + n_atoms[s];
        out_ns[s] = tstarts[bhi] - tstarts[blo];
    }

    int wv = threadIdx.x >> 6;
    int lane = threadIdx.x & 63;
    int a = blockIdx.x * FWPB + wv;
    if (a >= A) return;

    int4 m = meta[a];
    int c = m.x;
    if (c < 2) return;
    int st0 = m.y;
    int P = (c * (c - 1)) >> 1;
    int2* outp = out_bi + m.z;

    if (c <= 64) {
        int v = (lane < c) ? sorted_bond[st0 + lane] : 0x7fffffff;
        int rank = 0;
        for (int j = 0; j < c; ++j) {
            int vj = __shfl(v, j, 64);
            rank += (vj < v) ? 1 : 0;
        }
        int sv = __builtin_amdgcn_ds_permute(rank << 2, v);

        int niter = (P + 63) >> 6;
        for (int it = 0; it < niter; ++it) {
            int p = (it << 6) + lane;
            bool act = p < P;
            int pp = act ? p : 0;
            int i = 0, rem = pp;
            while (rem >= c - 1 - i) { rem -= c - 1 - i; ++i; }
            int j = i + 1 + rem;
            int bi = __shfl(sv, i, 64);
            int bj = __shfl(sv, j, 64);
            if (act) {
                outp[p]     = make_int2(bi, bj);
                outp[P + p] = make_int2(bj, bi);
            }
        }
    } else if (lane == 0) {
        for (int i = 1; i < c; ++i) {
            int v = sorted_bond[st0 + i];
            int j = i - 1;
            while (j >= 0 && sorted_bond[st0 + j] > v) {
                sorted_bond[st0 + j + 1] = sorted_bond[st0 + j];
                --j;
            }
            sorted_bond[st0 + j + 1] = v;
        }
        int p = 0;
        for (int i = 0; i < c; ++i) {
            int bi = sorted_bond[st0 + i];
            for (int j = i + 1; j < c; ++j) {
                int bj = sorted_bond[st0 + j];
                outp[p]     = make_int2(bi, bj);
                outp[P + p] = make_int2(bj, bi);
                ++p;
            }
        }
    }
}

extern "C" void kernel_launch(void* const* d_in, const int* in_sizes, int n_in,
                              void* d_out, int out_size, void* d_ws, size_t ws_size,
                              hipStream_t stream) {
    const int2* bai     = (const int2*)d_in[0];   // [n_bond,2] int32
    const float* blen   = (const float*)d_in[1];  // [n_bond] f32
    const int* n_atoms  = (const int*)d_in[2];    // [S] int32
    // d_in[3] = atomic_number (unused)
    const float* cutp   = (const float*)d_in[4];  // scalar f32

    int n_bond = in_sizes[1];
    int S      = in_sizes[2];
    int A      = in_sizes[3];

    int n_tr2 = out_size - n_bond - A - S;  // 2 * n_triple

    int* out     = (int*)d_out;
    int2* out_bi = (int2*)out;          // [n_triple] pairs
    int* out_ij  = out + n_tr2;         // [n_bond]
    int* out_ti  = out_ij + n_bond;     // [A]
    int* out_ns  = out_ti + A;          // [S]

    int* ws = (int*)d_ws;
    int NC = (A + SBLK - 1) / SBLK;

    // fast-path layout
    int meta2_off = (A + 3 * NC + 1) & ~1;          // int2 needs 8B align
    long long need_fast = (long long)meta2_off + 3LL * A + 1 + 64LL * A;
    bool fast = ((long long)(ws_size / 4) >= need_fast) && (NC <= 1024) &&
                (S <= 64) && ((A & 1) == 0);

    if (fast) {
        int* cursor   = ws;                          // A
        u64* lb       = (u64*)(ws + A);              // NC u64
        int* tdone    = ws + A + 2 * NC;             // NC
        int2* meta2   = (int2*)(ws + meta2_off);     // A int2
        int* tstarts  = ws + meta2_off + 2 * A;      // A+1
        int* bucket   = ws + meta2_off + 3 * A + 1;  // 64*A

        int NP = (A + WPB - 1) / WPB;                // 4 atoms (waves) per block

        k_init<<<(A + 3 * NC + 255) / 256, 256, 0, stream>>>(cursor, A + 3 * NC);
        kf_bucket<<<(n_bond + 255) / 256, 256, 0, stream>>>(bai, blen, cutp, cursor,
                                                            bucket, out_ij, n_bond);
        kf_scanpairs<<<NP, SBLK, 0, stream>>>(cursor, lb, tdone, meta2, tstarts,
                                              out_ti, bucket, out_bi, out_ij,
                                              n_atoms, out_ns, S, A, NC);
    } else {
        int* counts      = ws;
        int* cursor      = ws + A;
        int* starts      = ws + 2 * A;
        int* tstarts     = ws + 3 * A;                  // A+1, padded to 4A+4
        int4* meta       = (int4*)(ws + 4 * A + 4);
        int* sorted_bond = ws + 8 * A + 4;
        int2* partials   = (int2*)(ws + 8 * A + 4 + n_bond);
        int NB = (A + BLK - 1) / BLK;

        k_init<<<(A + 255) / 256, 256, 0, stream>>>(counts, A);
        k_count<<<(n_bond + 255) / 256, 256, 0, stream>>>(bai, blen, cutp, counts, n_bond);
        k_part<<<NB, BLK, 0, stream>>>(counts, partials, A);
        k_mid<<<1, 1024, 0, stream>>>(partials, NB, &tstarts[A]);
        k_final<<<NB, BLK, 0, stream>>>(counts, partials, starts, tstarts, meta, out_ti,
                                        cursor, A);
        k_scatter<<<(n_bond + 255) / 256, 256, 0, stream>>>(bai, blen, cutp, meta,
                                                            cursor, sorted_bond, out_ij,
                                                            n_bond);
        k_pairs<<<(A + FWPB - 1) / FWPB, FWPB * 64, 0, stream>>>(meta, sorted_bond,
                                                                 out_bi, tstarts,
                                                                 n_atoms, out_ns, S, A);
    }
}

// Round 16
// 39.477 us; speedup vs baseline: 13.0453x; 3.9881x over previous
//
#include <hip/hip_runtime.h>

typedef unsigned long long u64;

// ---------------------------------------------------------------------------
// threebody indices (MatterSim). All outputs int32.
//
// FAST path ws layout (int32):
//   [0, A)                 cursor (zeroed; counts after bucket pass)
//   [A, A+2*NC)            lb     (u64 lookback flags: state<<32 | value)
//   [A+2NC, 2A+2NC+1)      tstarts (exclusive scan of c*(c-1); [A]=total)
//   [2A+2NC+2, 4A+2NC+2)   meta2  (int2 per atom: {c, tstart})
//   [4A+2NC+2, 68A+2NC+2)  bucket (CMAX ints per atom)
//
// FALLBACK (round-7) ws layout: counts A | cursor A | starts A | tstarts A+1
//   (pad 4A+4) | meta int4 4A | sorted_bond n_bond | partials 2*NB
// ---------------------------------------------------------------------------

#define CMAX 64    // padded bucket capacity per atom (data max ~30)
#define SBLK 256   // scan tile size
#define WPB 8      // waves (atoms) per block in kf_pairs
#define FWPB 4     // fallback k_pairs waves/block
#define BLK 256    // fallback scan block size

__global__ void k_init(int* __restrict__ p, int n) {
    int i = blockIdx.x * blockDim.x + threadIdx.x;
    if (i < n) p[i] = 0;
}

// ============================ FAST PATH ====================================

// One pass over bonds: zero out_ij, scatter kept bonds into padded buckets.
__global__ void kf_bucket(const int2* __restrict__ bai, const float* __restrict__ blen,
                          const float* __restrict__ cutp, int* __restrict__ cursor,
                          int* __restrict__ bucket, int* __restrict__ out_ij,
                          int n_bond) {
    int b = blockIdx.x * blockDim.x + threadIdx.x;
    if (b >= n_bond) return;
    out_ij[b] = 0;                       // kept bonds overwritten by kf_pairs
    if (blen[b] <= *cutp) {
        int a = bai[b].x;
        int r = atomicAdd(&cursor[a], 1);
        if (r < CMAX) bucket[(a << 6) + r] = b;
    }
}

// Single-pass decoupled-lookback exclusive scan of t = c*(c-1) over atoms.
// Lookback is WAVE-PARALLEL: 64 lanes inspect a 64-wide predecessor window
// at once (<=2 dependent rounds for NC<=128, vs serial walk ~NC rounds).
// Writes tstarts (+ total at [A]), meta2 {c, tstart}, out_ti.
__global__ __launch_bounds__(SBLK) void kf_scan(const int* __restrict__ cursor,
                                                u64* __restrict__ lb,
                                                int* __restrict__ tstarts,
                                                int2* __restrict__ meta2,
                                                int* __restrict__ out_ti, int A) {
    int blk = blockIdx.x;
    int i = blk * SBLK + threadIdx.x;
    int lane = threadIdx.x & 63, wv = threadIdx.x >> 6;

    int c = 0;
    if (i < A) {
        c = cursor[i];
        if (c > CMAX) c = CMAX;          // memory-safety clamp (never hit here)
    }
    int t = c * (c - 1);

    int it = t;                           // inclusive wave scan of t
    for (int off = 1; off < 64; off <<= 1) {
        int nt = __shfl_up(it, off, 64);
        if (lane >= off) it += nt;
    }
    __shared__ int wt[SBLK / 64];
    __shared__ int s_ex;
    if (lane == 63) wt[wv] = it;
    __syncthreads();
    int bt = 0;
    for (int w = 0; w < wv; ++w) bt += wt[w];
    int tile_ex = bt + it - t;            // exclusive offset within tile

    // block aggregate (all threads can compute from wt)
    int agg = 0;
    for (int w = 0; w < SBLK / 64; ++w) agg += wt[w];

    if (blk == 0) {
        if (threadIdx.x == 0) {
            __hip_atomic_store(&lb[0], (2ull << 32) | (u64)(unsigned)agg,
                               __ATOMIC_RELEASE, __HIP_MEMORY_SCOPE_AGENT);
            s_ex = 0;
        }
    } else if (wv == 0) {
        if (lane == 0)
            __hip_atomic_store(&lb[blk], (1ull << 32) | (u64)(unsigned)agg,
                               __ATOMIC_RELEASE, __HIP_MEMORY_SCOPE_AGENT);
        int ex = 0;
        int base = blk - 1;
        for (;;) {
            int j = base - lane;          // lane 0 = nearest predecessor
            unsigned st;
            int val;
            if (j >= 0) {
                u64 v = __hip_atomic_load(&lb[j], __ATOMIC_ACQUIRE,
                                          __HIP_MEMORY_SCOPE_AGENT);
                st = (unsigned)(v >> 32);
                val = (int)(unsigned)(v & 0xffffffffull);
            } else {                      // below block 0: virtual prefix 0
                st = 2u;
                val = 0;
            }
            u64 b2 = __ballot(st == 2u);
            u64 b0 = __ballot(st == 0u);
            int L2 = b2 ? __builtin_ctzll(b2) : 64;   // first inclusive prefix
            u64 need = (L2 >= 63) ? ~0ull : ((1ull << (L2 + 1)) - 1ull);
            if ((b0 & need) == 0) {       // all needed entries published
                int vsum = (L2 >= 64 || lane <= L2) ? val : 0;
                for (int off = 32; off; off >>= 1)
                    vsum += __shfl_xor(vsum, off, 64);
                ex += vsum;
                if (L2 < 64) break;       // consumed an inclusive prefix: done
                base -= 64;               // window was all aggregates: continue
            }
            // else: some predecessor not ready — re-poll same window
        }
        if (lane == 0) {
            __hip_atomic_store(&lb[blk],
                               (2ull << 32) | (u64)(unsigned)(ex + agg),
                               __ATOMIC_RELEASE, __HIP_MEMORY_SCOPE_AGENT);
            s_ex = ex;
        }
    }
    __syncthreads();

    int tx = s_ex + tile_ex;
    if (i < A) {
        tstarts[i] = tx;
        meta2[i] = make_int2(c, tx);
        out_ti[i] = t;
        if (i == A - 1) tstarts[A] = tx + t;
    }
}

// One wave per atom, WPB atoms per block. Coalesced 64-int bucket read,
// scatter out_ij = c-1, wave-parallel rank sort (bond ids unique), coalesced
// int2 pair emission: forward block [bi,bj], then flipped block [bj,bi].
// Block 0 also writes out_ns from tstarts differences.
__global__ __launch_bounds__(WPB * 64) void kf_pairs(
        const int2* __restrict__ meta2, const int* __restrict__ bucket,
        int2* __restrict__ out_bi, int* __restrict__ out_ij,
        const int* __restrict__ tstarts, const int* __restrict__ n_atoms,
        int* __restrict__ out_ns, int S, int A) {
    if (blockIdx.x == 0 && threadIdx.x < S) {
        int s = threadIdx.x;
        int blo = 0;
        for (int k = 0; k < s; ++k) blo += n_atoms[k];
        int bhi = blo + n_atoms[s];
        out_ns[s] = tstarts[bhi] - tstarts[blo];
    }

    int wv = threadIdx.x >> 6;
    int lane = threadIdx.x & 63;
    int a = blockIdx.x * WPB + wv;
    if (a >= A) return;

    int2 m = meta2[a];
    int c = m.x;
    if (c < 1) return;

    int v = (lane < c) ? bucket[(a << 6) + lane] : 0x7fffffff;
    if (lane < c) out_ij[v] = c - 1;      // covers c==1 (writes 0) and c>=2
    if (c < 2) return;

    int rank = 0;
    for (int j = 0; j < c; ++j) {
        int vj = __shfl(v, j, 64);
        rank += (vj < v) ? 1 : 0;
    }
    int sv = __builtin_amdgcn_ds_permute(rank << 2, v);

    int P = (c * (c - 1)) >> 1;           // (i<j) combos
    int2* outp = out_bi + m.y;            // atom block: 2P int2 (P fwd + P flip)
    int niter = (P + 63) >> 6;
    for (int it = 0; it < niter; ++it) {
        int p = (it << 6) + lane;
        bool act = p < P;
        int pp = act ? p : 0;
        int i = 0, rem = pp;
        while (rem >= c - 1 - i) { rem -= c - 1 - i; ++i; }
        int j = i + 1 + rem;
        int bi = __shfl(sv, i, 64);
        int bj = __shfl(sv, j, 64);
        if (act) {
            outp[p]     = make_int2(bi, bj);
            outp[P + p] = make_int2(bj, bi);
        }
    }
}

// =========================== FALLBACK (round 7) ============================
__global__ void k_count(const int2* __restrict__ bai, const float* __restrict__ blen,
                        const float* __restrict__ cutp, int* __restrict__ counts,
                        int n_bond) {
    int b = blockIdx.x * blockDim.x + threadIdx.x;
    if (b >= n_bond) return;
    if (blen[b] <= *cutp) atomicAdd(&counts[bai[b].x], 1);
}

__global__ __launch_bounds__(BLK) void k_part(const int* __restrict__ counts,
                                              int2* __restrict__ partials, int A) {
    int i = blockIdx.x * BLK + threadIdx.x;
    int c = (i < A) ? counts[i] : 0;
    int t = c * (c - 1);
    int lane = threadIdx.x & 63, wv = threadIdx.x >> 6;
    for (int off = 32; off; off >>= 1) {
        c += __shfl_down(c, off, 64);
        t += __shfl_down(t, off, 64);
    }
    __shared__ int sc[BLK / 64], st[BLK / 64];
    if (lane == 0) { sc[wv] = c; st[wv] = t; }
    __syncthreads();
    if (threadIdx.x == 0) {
        int tc = 0, tt = 0;
        for (int w = 0; w < BLK / 64; ++w) { tc += sc[w]; tt += st[w]; }
        partials[blockIdx.x] = make_int2(tc, tt);
    }
}

__global__ __launch_bounds__(1024) void k_mid(int2* __restrict__ partials, int NB,
                                              int* __restrict__ totp) {
    const int T = 1024;
    __shared__ int sc[T], st[T];
    int tid = threadIdx.x;
    int chunk = (NB + T - 1) / T;
    int lo = tid * chunk, hi = lo + chunk;
    if (hi > NB) hi = NB;
    int pc = 0, pt = 0;
    for (int i = lo; i < hi; ++i) { pc += partials[i].x; pt += partials[i].y; }
    sc[tid] = pc; st[tid] = pt;
    __syncthreads();
    for (int off = 1; off < T; off <<= 1) {
        int vc = 0, vt = 0;
        if (tid >= off) { vc = sc[tid - off]; vt = st[tid - off]; }
        __syncthreads();
        sc[tid] += vc; st[tid] += vt;
        __syncthreads();
    }
    int rc = sc[tid] - pc, rt = st[tid] - pt;
    for (int i = lo; i < hi; ++i) {
        int2 v = partials[i];
        partials[i] = make_int2(rc, rt);
        rc += v.x; rt += v.y;
    }
    if (tid == T - 1) *totp = rt;
}

__global__ __launch_bounds__(BLK) void k_final(const int* __restrict__ counts,
                                               const int2* __restrict__ partials,
                                               int* __restrict__ starts,
                                               int* __restrict__ tstarts,
                                               int4* __restrict__ meta,
                                               int* __restrict__ out_ti,
                                               int* __restrict__ cursor, int A) {
    int i = blockIdx.x * BLK + threadIdx.x;
    int c = (i < A) ? counts[i] : 0;
    int t = c * (c - 1);
    int lane = threadIdx.x & 63, wv = threadIdx.x >> 6;
    int ic = c, it = t;
    for (int off = 1; off < 64; off <<= 1) {
        int nc = __shfl_up(ic, off, 64), nt = __shfl_up(it, off, 64);
        if (lane >= off) { ic += nc; it += nt; }
    }
    __shared__ int wc[BLK / 64], wt[BLK / 64];
    if (lane == 63) { wc[wv] = ic; wt[wv] = it; }
    __syncthreads();
    int bc = 0, bt = 0;
    for (int w = 0; w < wv; ++w) { bc += wc[w]; bt += wt[w]; }
    int2 bo = partials[blockIdx.x];
    int sx = bo.x + bc + ic - c;
    int tx = bo.y + bt + it - t;
    if (i < A) {
        starts[i] = sx;
        tstarts[i] = tx;
        meta[i] = make_int4(c, sx, tx, 0);
        out_ti[i] = t;
        cursor[i] = sx;
        if (i == A - 1) tstarts[A] = tx + t;
    }
}

__global__ void k_scatter(const int2* __restrict__ bai, const float* __restrict__ blen,
                          const float* __restrict__ cutp, const int4* __restrict__ meta,
                          int* __restrict__ cursor, int* __restrict__ sorted_bond,
                          int* __restrict__ out_ij, int n_bond) {
    int b = blockIdx.x * blockDim.x + threadIdx.x;
    if (b >= n_bond) return;
    if (blen[b] <= *cutp) {
        int c = bai[b].x;
        int cnt = meta[c].x;
        out_ij[b] = cnt > 1 ? cnt - 1 : 0;
        int r = atomicAdd(&cursor[c], 1);
        sorted_bond[r] = b;
    } else {
        out_ij[b] = 0;
    }
}

__global__ __launch_bounds__(FWPB * 64) void k_pairs(
        const int4* __restrict__ meta, int* __restrict__ sorted_bond,
        int2* __restrict__ out_bi, const int* __restrict__ tstarts,
        const int* __restrict__ n_atoms, int* __restrict__ out_ns,
        int S, int A) {
    if (blockIdx.x == 0 && threadIdx.x < S) {
        int s = threadIdx.x;
        int blo = 0;
        for (int k = 0; k < s; ++k) blo += n_atoms[k];
        int bhi = blo + n_atoms[s];
        out_ns[s] = tstarts[bhi] - tstarts[blo];
    }

    int wv = threadIdx.x >> 6;
    int lane = threadIdx.x & 63;
    int a = blockIdx.x * FWPB + wv;
    if (a >= A) return;

    int4 m = meta[a];
    int c = m.x;
    if (c < 2) return;
    int st0 = m.y;
    int P = (c * (c - 1)) >> 1;
    int2* outp = out_bi + m.z;

    if (c <= 64) {
        int v = (lane < c) ? sorted_bond[st0 + lane] : 0x7fffffff;
        int rank = 0;
        for (int j = 0; j < c; ++j) {
            int vj = __shfl(v, j, 64);
            rank += (vj < v) ? 1 : 0;
        }
        int sv = __builtin_amdgcn_ds_permute(rank << 2, v);

        int niter = (P + 63) >> 6;
        for (int it = 0; it < niter; ++it) {
            int p = (it << 6) + lane;
            bool act = p < P;
            int pp = act ? p : 0;
            int i = 0, rem = pp;
            while (rem >= c - 1 - i) { rem -= c - 1 - i; ++i; }
            int j = i + 1 + rem;
            int bi = __shfl(sv, i, 64);
            int bj = __shfl(sv, j, 64);
            if (act) {
                outp[p]     = make_int2(bi, bj);
                outp[P + p] = make_int2(bj, bi);
            }
        }
    } else if (lane == 0) {
        for (int i = 1; i < c; ++i) {
            int v = sorted_bond[st0 + i];
            int j = i - 1;
            while (j >= 0 && sorted_bond[st0 + j] > v) {
                sorted_bond[st0 + j + 1] = sorted_bond[st0 + j];
                --j;
            }
            sorted_bond[st0 + j + 1] = v;
        }
        int p = 0;
        for (int i = 0; i < c; ++i) {
            int bi = sorted_bond[st0 + i];
            for (int j = i + 1; j < c; ++j) {
                int bj = sorted_bond[st0 + j];
                outp[p]     = make_int2(bi, bj);
                outp[P + p] = make_int2(bj, bi);
                ++p;
            }
        }
    }
}

extern "C" void kernel_launch(void* const* d_in, const int* in_sizes, int n_in,
                              void* d_out, int out_size, void* d_ws, size_t ws_size,
                              hipStream_t stream) {
    const int2* bai     = (const int2*)d_in[0];   // [n_bond,2] int32
    const float* blen   = (const float*)d_in[1];  // [n_bond] f32
    const int* n_atoms  = (const int*)d_in[2];    // [S] int32
    // d_in[3] = atomic_number (unused)
    const float* cutp   = (const float*)d_in[4];  // scalar f32

    int n_bond = in_sizes[1];
    int S      = in_sizes[2];
    int A      = in_sizes[3];

    int n_tr2 = out_size - n_bond - A - S;  // 2 * n_triple

    int* out     = (int*)d_out;
    int2* out_bi = (int2*)out;          // [n_triple] pairs
    int* out_ij  = out + n_tr2;         // [n_bond]
    int* out_ti  = out_ij + n_bond;     // [A]
    int* out_ns  = out_ti + A;          // [S]

    int* ws = (int*)d_ws;
    int NC = (A + SBLK - 1) / SBLK;

    // fast-path layout + size check
    long long need_fast = 68LL * A + 2 * NC + 2;
    bool fast = ((long long)(ws_size / 4) >= need_fast) && (NC <= 1024) && (S <= 64);

    if (fast) {
        int* cursor   = ws;                                // A
        u64* lb       = (u64*)(ws + A);                    // NC u64
        int* tstarts  = ws + A + 2 * NC;                   // A+1
        int2* meta2   = (int2*)(ws + 2 * A + 2 * NC + 2);  // A int2
        int* bucket   = ws + 4 * A + 2 * NC + 2;           // 64*A

        k_init<<<(A + 2 * NC + 255) / 256, 256, 0, stream>>>(cursor, A + 2 * NC);
        kf_bucket<<<(n_bond + 255) / 256, 256, 0, stream>>>(bai, blen, cutp, cursor,
                                                            bucket, out_ij, n_bond);
        kf_scan<<<NC, SBLK, 0, stream>>>(cursor, lb, tstarts, meta2, out_ti, A);
        kf_pairs<<<(A + WPB - 1) / WPB, WPB * 64, 0, stream>>>(meta2, bucket, out_bi,
                                                               out_ij, tstarts, n_atoms,
                                                               out_ns, S, A);
    } else {
        int* counts      = ws;
        int* cursor      = ws + A;
        int* starts      = ws + 2 * A;
        int* tstarts     = ws + 3 * A;                  // A+1, padded to 4A+4
        int4* meta       = (int4*)(ws + 4 * A + 4);
        int* sorted_bond = ws + 8 * A + 4;
        int2* partials   = (int2*)(ws + 8 * A + 4 + n_bond);
        int NB = (A + BLK - 1) / BLK;

        k_init<<<(A + 255) / 256, 256, 0, stream>>>(counts, A);
        k_count<<<(n_bond + 255) / 256, 256, 0, stream>>>(bai, blen, cutp, counts, n_bond);
        k_part<<<NB, BLK, 0, stream>>>(counts, partials, A);
        k_mid<<<1, 1024, 0, stream>>>(partials, NB, &tstarts[A]);
        k_final<<<NB, BLK, 0, stream>>>(counts, partials, starts, tstarts, meta, out_ti,
                                        cursor, A);
        k_scatter<<<(n_bond + 255) / 256, 256, 0, stream>>>(bai, blen, cutp, meta,
                                                            cursor, sorted_bond, out_ij,
                                                            n_bond);
        k_pairs<<<(A + FWPB - 1) / FWPB, FWPB * 64, 0, stream>>>(meta, sorted_bond,
                                                                 out_bi, tstarts,
                                                                 n_atoms, out_ns, S, A);
    }
}